// Round 1
// baseline (175.382 us; speedup 1.0000x reference)
//
#include <hip/hip_runtime.h>

#define NT 32
#define START_TAG 30
#define STOP_TAG 31
#define L2E 1.4426950408889634f
#define LN2 0.6931471805599453f
#define EBLK 128

// frexp-style exponent: for normal m>0, m in [2^(e-1), 2^e)
__device__ __forceinline__ int fexp_of(float m) {
  return (int)((__float_as_uint(m) >> 23) & 255u) - 126;
}

// ---------------------------------------------------------------------------
// K1: each block computes the prob-space product of its chunk's step operators
//     M_chunk = diag(E_{last})·P ··· diag(E_{first})·P      (32x32)
// stored column-normalized to [0.5,1) with per-column log2 offsets.
// Thread tile: rows {rp, rp+16} x 4 columns. P rows live in registers.
// ---------------------------------------------------------------------------
__global__ __launch_bounds__(128) void crf_k1(
    const float* __restrict__ feat, const float* __restrict__ trans,
    float* __restrict__ wmat, float* __restrict__ woff, int lch)
{
  const int tid = threadIdx.x;
  const int c = blockIdx.x;
  const int rp = tid >> 3;          // 0..15
  const int cq = (tid & 7) << 2;    // 0,4,...,28
  const int r0 = rp, r1 = rp + 16;

  __shared__ __align__(16) float E[EBLK * NT];      // exp2 of emissions block
  __shared__ __align__(16) float Cb[2][NT][36];     // ping-pong C (pad 36)
  __shared__ __align__(16) float fac[NT];           // per-col ldexp shift
  __shared__ __align__(16) float offs[NT];          // per-col log2 offset

  // P = exp(trans) rows in registers (base-2 logs: exp2(trans*log2e))
  float p0[NT], p1[NT];
#pragma unroll
  for (int j = 0; j < NT; ++j) {
    p0[j] = exp2f(trans[r0 * NT + j] * L2E);
    p1[j] = exp2f(trans[r1 * NT + j] * L2E);
  }

  // init C = I * 2^-48 (headroom anchor), offs = 48
#pragma unroll
  for (int q = 0; q < 4; ++q) {
    Cb[0][r0][cq + q] = (r0 == cq + q) ? 0x1p-48f : 0.0f;
    Cb[0][r1][cq + q] = (r1 == cq + q) ? 0x1p-48f : 0.0f;
  }
  if (tid < NT) offs[tid] = 48.0f;

  const int t0 = c * lch;
  float4 A0 = make_float4(0.f,0.f,0.f,0.f), A1 = A0;

  for (int sb = 0; sb < lch; sb += EBLK) {
    __syncthreads();
    // preload E block: EBLK*NT floats, coalesced float4, exp2 on the fly
    const float4* f4 = (const float4*)(feat + (size_t)(t0 + sb) * NT);
    float4* E4 = (float4*)E;
#pragma unroll
    for (int b = 0; b < 8; ++b) {
      float4 v = f4[b * 128 + tid];
      float4 e;
      e.x = exp2f(v.x * L2E); e.y = exp2f(v.y * L2E);
      e.z = exp2f(v.z * L2E); e.w = exp2f(v.w * L2E);
      E4[b * 128 + tid] = e;
    }
    __syncthreads();

    for (int s = 0; s < EBLK; ++s) {
      const int gs = sb + s;
      const int cur = gs & 1, nxt = cur ^ 1;
      const float e0 = E[s * NT + r0];
      const float e1 = E[s * NT + r1];
      A0 = make_float4(0.f,0.f,0.f,0.f);
      A1 = make_float4(0.f,0.f,0.f,0.f);
#pragma unroll
      for (int j = 0; j < NT; ++j) {
        const float4 cj = *(const float4*)&Cb[cur][j][cq];
        A0.x += p0[j]*cj.x; A0.y += p0[j]*cj.y; A0.z += p0[j]*cj.z; A0.w += p0[j]*cj.w;
        A1.x += p1[j]*cj.x; A1.y += p1[j]*cj.y; A1.z += p1[j]*cj.z; A1.w += p1[j]*cj.w;
      }
      A0.x *= e0; A0.y *= e0; A0.z *= e0; A0.w *= e0;
      A1.x *= e1; A1.y *= e1; A1.z *= e1; A1.w *= e1;
      *(float4*)&Cb[nxt][r0][cq] = A0;
      *(float4*)&Cb[nxt][r1][cq] = A1;
      __syncthreads();

      if ((gs & 7) == 7) {   // renorm columns to ~2^-48 every 8 steps
        if (tid < NT) {
          float m = 0.0f;
#pragma unroll
          for (int j = 0; j < NT; ++j) m = fmaxf(m, Cb[nxt][j][tid]);
          float k = 0.0f;
          if (m > 0.0f) {
            int ex = fexp_of(m);
            k = -(float)(ex + 48);
            offs[tid] += (float)(ex + 48);
          }
          fac[tid] = k;
        }
        __syncthreads();
        const float4 kq = *(const float4*)&fac[cq];
        A0.x = ldexpf(A0.x,(int)kq.x); A0.y = ldexpf(A0.y,(int)kq.y);
        A0.z = ldexpf(A0.z,(int)kq.z); A0.w = ldexpf(A0.w,(int)kq.w);
        A1.x = ldexpf(A1.x,(int)kq.x); A1.y = ldexpf(A1.y,(int)kq.y);
        A1.z = ldexpf(A1.z,(int)kq.z); A1.w = ldexpf(A1.w,(int)kq.w);
        *(float4*)&Cb[nxt][r0][cq] = A0;
        *(float4*)&Cb[nxt][r1][cq] = A1;
        __syncthreads();
      }
    }
  }

  // final renorm to [0.5,1) and store. lch even -> final buffer is 0,
  // and (lch-1)&7==7 -> regs A0/A1 match Cb[0].
  if (tid < NT) {
    float m = 0.0f;
#pragma unroll
    for (int j = 0; j < NT; ++j) m = fmaxf(m, Cb[0][j][tid]);
    float k = 0.0f;
    if (m > 0.0f) {
      int ex = fexp_of(m);
      k = -(float)ex;
      offs[tid] += (float)ex;
    }
    fac[tid] = k;
  }
  __syncthreads();
  {
    const float4 kq = *(const float4*)&fac[cq];
    A0.x = ldexpf(A0.x,(int)kq.x); A0.y = ldexpf(A0.y,(int)kq.y);
    A0.z = ldexpf(A0.z,(int)kq.z); A0.w = ldexpf(A0.w,(int)kq.w);
    A1.x = ldexpf(A1.x,(int)kq.x); A1.y = ldexpf(A1.y,(int)kq.y);
    A1.z = ldexpf(A1.z,(int)kq.z); A1.w = ldexpf(A1.w,(int)kq.w);
    float* dst = wmat + (size_t)c * (NT*NT);
    *(float4*)&dst[r0 * NT + cq] = A0;
    *(float4*)&dst[r1 * NT + cq] = A1;
    if (tid < NT) woff[c * NT + tid] = offs[tid];
  }
}

// ---------------------------------------------------------------------------
// K2: combine groups of `grp` consecutive chunk matrices chronologically:
//     G = M_{c0+grp-1} ··· M_{c0}
// offsets folded via w[j] = 2^(moff_j - max moff); renorm every step.
// ---------------------------------------------------------------------------
__global__ __launch_bounds__(128) void crf_k2(
    const float* __restrict__ wmat, const float* __restrict__ woff,
    float* __restrict__ w2mat, float* __restrict__ w2off, int grp)
{
  const int tid = threadIdx.x;
  const int g = blockIdx.x;
  const int c0 = g * grp;
  const int rp = tid >> 3;
  const int cq = (tid & 7) << 2;
  const int r0 = rp, r1 = rp + 16;

  __shared__ __align__(16) float Gb[2][NT][36];
  __shared__ __align__(16) float wj[NT];
  __shared__ __align__(16) float goff[NT];
  __shared__ __align__(16) float fac[NT];

  {
    const float* M0 = wmat + (size_t)c0 * (NT*NT);
    *(float4*)&Gb[0][r0][cq] = *(const float4*)&M0[r0*NT+cq];
    *(float4*)&Gb[0][r1][cq] = *(const float4*)&M0[r1*NT+cq];
    if (tid < NT) goff[tid] = woff[c0*NT + tid];
  }
  __syncthreads();

  float4 A0 = make_float4(0.f,0.f,0.f,0.f), A1 = A0;
  // if grp==1 we still must populate regs for the store path
  A0 = *(const float4*)&Gb[0][r0][cq];
  A1 = *(const float4*)&Gb[0][r1][cq];

  for (int gg = 1; gg < grp; ++gg) {
    const float* M = wmat + (size_t)(c0 + gg) * (NT*NT);
    float a0[NT], a1[NT];
#pragma unroll
    for (int b = 0; b < 8; ++b) {
      float4 v0 = *(const float4*)&M[r0*NT + 4*b];
      float4 v1 = *(const float4*)&M[r1*NT + 4*b];
      a0[4*b]=v0.x; a0[4*b+1]=v0.y; a0[4*b+2]=v0.z; a0[4*b+3]=v0.w;
      a1[4*b]=v1.x; a1[4*b+1]=v1.y; a1[4*b+2]=v1.z; a1[4*b+3]=v1.w;
    }
    float mm = 0.0f;
    if (tid < NT) {
      float mo = woff[(c0 + gg)*NT + tid];
      mm = mo;
#pragma unroll
      for (int d = 16; d; d >>= 1) mm = fmaxf(mm, __shfl_xor(mm, d, 64));
      wj[tid] = exp2f(mo - mm);
    }
    __syncthreads();

    const int cur = (gg - 1) & 1, nxt = gg & 1;
    A0 = make_float4(0.f,0.f,0.f,0.f);
    A1 = make_float4(0.f,0.f,0.f,0.f);
#pragma unroll
    for (int j = 0; j < NT; ++j) {
      const float wv = wj[j];
      const float4 gj = *(const float4*)&Gb[cur][j][cq];
      const float b0 = a0[j]*wv, b1 = a1[j]*wv;
      A0.x += b0*gj.x; A0.y += b0*gj.y; A0.z += b0*gj.z; A0.w += b0*gj.w;
      A1.x += b1*gj.x; A1.y += b1*gj.y; A1.z += b1*gj.z; A1.w += b1*gj.w;
    }
    *(float4*)&Gb[nxt][r0][cq] = A0;
    *(float4*)&Gb[nxt][r1][cq] = A1;
    __syncthreads();

    if (tid < NT) {  // renorm to [0.5,1); fold mm into offsets
      float m = 0.0f;
#pragma unroll
      for (int j = 0; j < NT; ++j) m = fmaxf(m, Gb[nxt][j][tid]);
      float k = 0.0f;
      float add = mm;
      if (m > 0.0f) { int ex = fexp_of(m); k = -(float)ex; add += (float)ex; }
      fac[tid] = k;
      goff[tid] += add;
    }
    __syncthreads();
    const float4 kq = *(const float4*)&fac[cq];
    A0.x = ldexpf(A0.x,(int)kq.x); A0.y = ldexpf(A0.y,(int)kq.y);
    A0.z = ldexpf(A0.z,(int)kq.z); A0.w = ldexpf(A0.w,(int)kq.w);
    A1.x = ldexpf(A1.x,(int)kq.x); A1.y = ldexpf(A1.y,(int)kq.y);
    A1.z = ldexpf(A1.z,(int)kq.z); A1.w = ldexpf(A1.w,(int)kq.w);
    *(float4*)&Gb[nxt][r0][cq] = A0;
    *(float4*)&Gb[nxt][r1][cq] = A1;
    __syncthreads();
  }

  float* dst = w2mat + (size_t)g * (NT*NT);
  *(float4*)&dst[r0*NT + cq] = A0;
  *(float4*)&dst[r1*NT + cq] = A1;
  if (tid < NT) w2off[g*NT + tid] = goff[tid];
}

// ---------------------------------------------------------------------------
// K3: apply the n2 group matrices to the init vector sequentially, then
// terminal LSE with transitions[STOP] row. Single wave.
// ---------------------------------------------------------------------------
__global__ __launch_bounds__(64) void crf_k3(
    const float* __restrict__ w2mat, const float* __restrict__ w2off,
    const float* __restrict__ trans, const float* __restrict__ init_al,
    float* __restrict__ out, int n2)
{
  const int tid = threadIdx.x;
  __shared__ __align__(16) float u[NT];
  float vsr = 0.0f, vo = 0.0f;
  if (tid < NT) vsr = exp2f(init_al[tid] * L2E);

  for (int g = 0; g < n2; ++g) {
    float mm = 0.0f;
    if (tid < NT) {
      float mo = w2off[g*NT + tid];
      mm = mo;
#pragma unroll
      for (int d = 16; d; d >>= 1) mm = fmaxf(mm, __shfl_xor(mm, d, 64));
      u[tid] = exp2f(mo - mm) * vsr;
    }
    __syncthreads();
    if (tid < NT) {
      const float* M = w2mat + (size_t)g * (NT*NT) + tid * NT;
      float acc = 0.0f;
#pragma unroll
      for (int k = 0; k < NT; ++k) acc += M[k] * u[k];
      float cm = acc;
#pragma unroll
      for (int d = 16; d; d >>= 1) cm = fmaxf(cm, __shfl_xor(cm, d, 64));
      int ex = fexp_of(cm);
      vsr = ldexpf(acc, -ex);
      vo += mm + (float)ex;
    }
    __syncthreads();
  }

  if (tid < NT) {
    float ts = trans[STOP_TAG * NT + tid] * L2E;
    float tm = ts;
#pragma unroll
    for (int d = 16; d; d >>= 1) tm = fmaxf(tm, __shfl_xor(tm, d, 64));
    float term = vsr * exp2f(ts - tm);
#pragma unroll
    for (int d = 16; d; d >>= 1) term += __shfl_xor(term, d, 64);
    if (tid == 0) out[0] = (vo + tm + log2f(term)) * LN2;
  }
}

extern "C" void kernel_launch(void* const* d_in, const int* in_sizes, int n_in,
                              void* d_out, int out_size, void* d_ws, size_t ws_size,
                              hipStream_t stream) {
  const float* feat    = (const float*)d_in[0];
  const float* trans   = (const float*)d_in[1];
  const float* init_al = (const float*)d_in[2];
  float* out = (float*)d_out;

  const int T = in_sizes[0] / NT;   // 65536

  // pick chunk count C fitting workspace; lch must be a multiple of EBLK
  int C = 512;
  while (C > 16) {
    size_t need = ((size_t)C * 1056 + (size_t)(C / 16) * 1056) * 4;
    if (need <= ws_size && (T % C) == 0 && ((T / C) % EBLK) == 0) break;
    C >>= 1;
  }
  const int lch = T / C;
  const int n2 = C / 16;

  float* wmat  = (float*)d_ws;
  float* woff  = wmat + (size_t)C * (NT*NT);
  float* w2mat = woff + (size_t)C * NT;
  float* w2off = w2mat + (size_t)n2 * (NT*NT);

  crf_k1<<<C, 128, 0, stream>>>(feat, trans, wmat, woff, lch);
  crf_k2<<<n2, 128, 0, stream>>>(wmat, woff, w2mat, w2off, 16);
  crf_k3<<<1, 64, 0, stream>>>(w2mat, w2off, trans, init_al, out, n2);
}

// Round 2
// 65.373 us; speedup vs baseline: 2.6828x; 2.6828x over previous
//
#include <hip/hip_runtime.h>

#define NT 32
#define START_TAG 30
#define STOP_TAG 31
#define L2E 1.4426950408889634f
#define LN2 0.6931471805599453f

typedef __attribute__((ext_vector_type(8))) short short8;
typedef __attribute__((ext_vector_type(16))) float f32x16;

// frexp-style exponent: for normal m>0, m in [2^(e-1), 2^e); 0/denorm -> -126
__device__ __forceinline__ int fexp_of(float m) {
  return (int)((__float_as_uint(m) >> 23) & 255u) - 126;
}

__device__ __forceinline__ unsigned pk_bf16(float lo, float hi) {
  unsigned r;
  asm("v_cvt_pk_bf16_f32 %0, %1, %2" : "=v"(r) : "v"(lo), "v"(hi));
  return r;
}

// sigma: storage-row permutation so that D-layout rows == next B-frag slots.
// slot k (k = i + 8h + 16g, i<8) holds true row (k&3) + 8*((k>>2)&1) + 4h + 16g
__device__ __forceinline__ int SIG(int k) {
  return (k & 3) + 8 * ((k >> 2) & 1) + 4 * ((k >> 3) & 1) + 16 * (k >> 4);
}
// D reg r (0..15) of lane-half h holds true row RHO(r,h)
__device__ __forceinline__ int RHO(int r, int h) {
  return (r & 3) + 8 * (r >> 2) + 4 * h;
}

struct Chain {
  short8 b0, b1;   // current state C in sigma-row-stored bf16 B-frags
  float m[16];     // last D (scaled), f32
  float offs;      // per-column log2 offset (column = lane&31)
};

__device__ __forceinline__ f32x16 mfma2(short8 a0, short8 a1, short8 b0, short8 b1) {
  f32x16 z = {};
  f32x16 d = __builtin_amdgcn_mfma_f32_32x32x16_bf16(a0, b0, z, 0, 0, 0);
  return __builtin_amdgcn_mfma_f32_32x32x16_bf16(a1, b1, d, 0, 0, 0);
}

__device__ __forceinline__ void k1_step(Chain& ch, const float* __restrict__ e,
                                        short8 pa0, short8 pa1, int h, bool rn) {
  const float4* e4 = (const float4*)e;
  float4 e0 = e4[h], e1 = e4[2 + h], e2 = e4[4 + h], e3 = e4[6 + h];
  f32x16 d = mfma2(pa0, pa1, ch.b0, ch.b1);
  ch.m[0] = d[0] * e0.x;  ch.m[1] = d[1] * e0.y;  ch.m[2] = d[2] * e0.z;  ch.m[3] = d[3] * e0.w;
  ch.m[4] = d[4] * e1.x;  ch.m[5] = d[5] * e1.y;  ch.m[6] = d[6] * e1.z;  ch.m[7] = d[7] * e1.w;
  ch.m[8] = d[8] * e2.x;  ch.m[9] = d[9] * e2.y;  ch.m[10] = d[10] * e2.z; ch.m[11] = d[11] * e2.w;
  ch.m[12] = d[12] * e3.x; ch.m[13] = d[13] * e3.y; ch.m[14] = d[14] * e3.z; ch.m[15] = d[15] * e3.w;
  if (rn) {
    float cm = ch.m[0];
#pragma unroll
    for (int i = 1; i < 16; ++i) cm = fmaxf(cm, ch.m[i]);
    cm = fmaxf(cm, __shfl_xor(cm, 32, 64));
    int ex = fexp_of(cm);
    ch.offs += (float)ex;
#pragma unroll
    for (int i = 0; i < 16; ++i) ch.m[i] = ldexpf(ch.m[i], -ex);
  }
  union { unsigned u[4]; short8 s; } B0, B1;
#pragma unroll
  for (int p = 0; p < 4; ++p) {
    B0.u[p] = pk_bf16(ch.m[2 * p], ch.m[2 * p + 1]);
    B1.u[p] = pk_bf16(ch.m[8 + 2 * p], ch.m[8 + 2 * p + 1]);
  }
  ch.b0 = B0.s; ch.b1 = B1.s;
}

__device__ __forceinline__ void init_identity(Chain& ch, int h, int c) {
  union { unsigned u[4]; short8 s; } B0, B1;
#pragma unroll
  for (int p = 0; p < 4; ++p) {
    unsigned lo0 = (SIG(8 * h + 2 * p) == c) ? 0x3F80u : 0u;
    unsigned hi0 = (SIG(8 * h + 2 * p + 1) == c) ? 0x3F80u : 0u;
    B0.u[p] = lo0 | (hi0 << 16);
    unsigned lo1 = (SIG(16 + 8 * h + 2 * p) == c) ? 0x3F80u : 0u;
    unsigned hi1 = (SIG(16 + 8 * h + 2 * p + 1) == c) ? 0x3F80u : 0u;
    B1.u[p] = lo1 | (hi1 << 16);
  }
  ch.b0 = B0.s; ch.b1 = B1.s; ch.offs = 0.f;
#pragma unroll
  for (int i = 0; i < 16; ++i) ch.m[i] = 0.f;
}

extern __shared__ float Els[];

// ---------------------------------------------------------------------------
// K1: one wave per block, TWO chunks per wave (ILP). Per step:
//     D = P_sigma * C   (2 x mfma 32x32x16 bf16),  C' = diag(E_t) * D
// No barriers in the main loop; renorm every 4 steps (exact power-of-2).
// ---------------------------------------------------------------------------
__global__ __launch_bounds__(64) void crf_k1(
    const float* __restrict__ feat, const float* __restrict__ trans,
    float* __restrict__ wmat, float* __restrict__ woff, int lch) {
  const int lane = threadIdx.x;
  const int h = lane >> 5, c = lane & 31;
  const int c0 = blockIdx.x * 2;

  // stage E = exp2(feat * log2e) for both chunks (contiguous in time)
  const float4* src = (const float4*)(feat + (size_t)c0 * lch * NT);
  float4* dst = (float4*)Els;
  const int n4 = lch * 16;  // float4 count for 2 chunks
  for (int k = lane; k < n4; k += 64) {
    float4 v = src[k];
    v.x = exp2f(v.x * L2E); v.y = exp2f(v.y * L2E);
    v.z = exp2f(v.z * L2E); v.w = exp2f(v.w * L2E);
    dst[k] = v;
  }

  // P A-frags, sigma-permuted columns: A0[i] = P[c][SIG(8h+i)], A1: +16
  short8 pa0, pa1;
  {
    union { unsigned u[4]; short8 s; } A0, A1;
#pragma unroll
    for (int p = 0; p < 4; ++p) {
      float f00 = exp2f(trans[c * NT + SIG(8 * h + 2 * p)] * L2E);
      float f01 = exp2f(trans[c * NT + SIG(8 * h + 2 * p + 1)] * L2E);
      float f10 = exp2f(trans[c * NT + SIG(16 + 8 * h + 2 * p)] * L2E);
      float f11 = exp2f(trans[c * NT + SIG(16 + 8 * h + 2 * p + 1)] * L2E);
      A0.u[p] = pk_bf16(f00, f01);
      A1.u[p] = pk_bf16(f10, f11);
    }
    pa0 = A0.s; pa1 = A1.s;
  }

  __syncthreads();

  Chain ch0, ch1;
  init_identity(ch0, h, c);
  init_identity(ch1, h, c);

  const float* eb0 = Els;
  const float* eb1 = Els + (size_t)lch * NT;
  for (int s = 0; s < lch; s += 4) {
#pragma unroll
    for (int t = 0; t < 4; ++t) {
      const bool rn = (t == 3);
      k1_step(ch0, eb0 + (s + t) * NT, pa0, pa1, h, rn);
      k1_step(ch1, eb1 + (s + t) * NT, pa0, pa1, h, rn);
    }
  }

  // store normalized chunk matrices row-major (true rows) + column offsets
  {
    float* wd = wmat + (size_t)c0 * 1024;
#pragma unroll
    for (int r = 0; r < 16; ++r) wd[RHO(r, h) * NT + c] = ch0.m[r];
    if (h == 0) woff[c0 * NT + c] = ch0.offs;
  }
  {
    float* wd = wmat + (size_t)(c0 + 1) * 1024;
#pragma unroll
    for (int r = 0; r < 16; ++r) wd[RHO(r, h) * NT + c] = ch1.m[r];
    if (h == 0) woff[(c0 + 1) * NT + c] = ch1.offs;
  }
}

// ---------------------------------------------------------------------------
// group_product: G = M_{c0+grp-1} ... M_{c0}, all via MFMA, barrier-free.
// Offsets: left matrix's column offsets scale the right product's rows.
// ---------------------------------------------------------------------------
__device__ __forceinline__ void group_product(
    const float* __restrict__ sm, const float* __restrict__ so,
    int c0, int grp, int h, int c, float m[16], float& offs) {
  const float* m0 = sm + (size_t)c0 * 1024;
#pragma unroll
  for (int r = 0; r < 16; ++r) m[r] = m0[RHO(r, h) * NT + c];
  offs = so[c0 * NT + c];

  for (int gg = 1; gg < grp; ++gg) {
    const float* M = sm + (size_t)(c0 + gg) * 1024;
    const float* O = so + (size_t)(c0 + gg) * NT;
    // A frags: row c of M, sigma-permuted columns
    float af[16];
#pragma unroll
    for (int i = 0; i < 8; ++i) {
      af[i] = M[c * NT + SIG(8 * h + i)];
      af[8 + i] = M[c * NT + SIG(16 + 8 * h + i)];
    }
    // offsets of left matrix: mm = max, w_row = 2^(mo_row - mm)
    float mo = O[c];
    float mm = mo;
#pragma unroll
    for (int dlt = 16; dlt; dlt >>= 1) mm = fmaxf(mm, __shfl_xor(mm, dlt, 64));
    const float4* o4 = (const float4*)O;
    float4 w0 = o4[h], w1 = o4[2 + h], w2 = o4[4 + h], w3 = o4[6 + h];
    float t[16];
    t[0] = m[0] * exp2f(w0.x - mm);  t[1] = m[1] * exp2f(w0.y - mm);
    t[2] = m[2] * exp2f(w0.z - mm);  t[3] = m[3] * exp2f(w0.w - mm);
    t[4] = m[4] * exp2f(w1.x - mm);  t[5] = m[5] * exp2f(w1.y - mm);
    t[6] = m[6] * exp2f(w1.z - mm);  t[7] = m[7] * exp2f(w1.w - mm);
    t[8] = m[8] * exp2f(w2.x - mm);  t[9] = m[9] * exp2f(w2.y - mm);
    t[10] = m[10] * exp2f(w2.z - mm); t[11] = m[11] * exp2f(w2.w - mm);
    t[12] = m[12] * exp2f(w3.x - mm); t[13] = m[13] * exp2f(w3.y - mm);
    t[14] = m[14] * exp2f(w3.z - mm); t[15] = m[15] * exp2f(w3.w - mm);

    union { unsigned u[4]; short8 s; } A0, A1, B0, B1;
#pragma unroll
    for (int p = 0; p < 4; ++p) {
      A0.u[p] = pk_bf16(af[2 * p], af[2 * p + 1]);
      A1.u[p] = pk_bf16(af[8 + 2 * p], af[8 + 2 * p + 1]);
      B0.u[p] = pk_bf16(t[2 * p], t[2 * p + 1]);
      B1.u[p] = pk_bf16(t[8 + 2 * p], t[8 + 2 * p + 1]);
    }
    f32x16 d = mfma2(A0.s, A1.s, B0.s, B1.s);
    float cm = d[0];
#pragma unroll
    for (int i = 1; i < 16; ++i) cm = fmaxf(cm, d[i]);
    cm = fmaxf(cm, __shfl_xor(cm, 32, 64));
    int ex = fexp_of(cm);
#pragma unroll
    for (int i = 0; i < 16; ++i) m[i] = ldexpf(d[i], -ex);
    offs += mm + (float)ex;
  }
}

__global__ __launch_bounds__(64) void crf_k2(
    const float* __restrict__ sm, const float* __restrict__ so,
    float* __restrict__ dm, float* __restrict__ dox, int grp) {
  const int lane = threadIdx.x;
  const int h = lane >> 5, c = lane & 31;
  const int g = blockIdx.x;
  float m[16], offs;
  group_product(sm, so, g * grp, grp, h, c, m, offs);
  float* wd = dm + (size_t)g * 1024;
#pragma unroll
  for (int r = 0; r < 16; ++r) wd[RHO(r, h) * NT + c] = m[r];
  if (h == 0) dox[g * NT + c] = offs;
}

// ---------------------------------------------------------------------------
// K3 (fused): n3 waves each combine 16 matrices -> LDS; then wave 0 runs the
// serial matvec chain from the one-hot START column + terminal LSE.
// ---------------------------------------------------------------------------
__global__ __launch_bounds__(512) void crf_k3(
    const float* __restrict__ sm, const float* __restrict__ so,
    const float* __restrict__ trans, float* __restrict__ out, int n3) {
  const int tid = threadIdx.x;
  const int wv = tid >> 6;
  const int lane = tid & 63;
  const int h = lane >> 5, c = lane & 31;
  __shared__ __align__(16) float Gls[8][1024];
  __shared__ __align__(16) float Ols[8][32];
  __shared__ __align__(16) float uls[32];

  {
    float m[16], offs;
    group_product(sm, so, wv * 16, 16, h, c, m, offs);
#pragma unroll
    for (int r = 0; r < 16; ++r) Gls[wv][RHO(r, h) * NT + c] = m[r];
    if (h == 0) Ols[wv][c] = offs;
  }
  __syncthreads();

  if (wv == 0) {
    float vh = Gls[0][c * NT + START_TAG];  // column START of first group
    float vo = Ols[0][START_TAG];
    for (int k = 1; k < n3; ++k) {
      float mo = Ols[k][c];
      float mm = mo;
#pragma unroll
      for (int dlt = 16; dlt; dlt >>= 1) mm = fmaxf(mm, __shfl_xor(mm, dlt, 64));
      if (h == 0) uls[c] = exp2f(mo - mm) * vh;
      asm volatile("s_waitcnt lgkmcnt(0)" ::: "memory");
      float acc = 0.f;
      const float4* Mr = (const float4*)&Gls[k][c * NT];
      const float4* uu = (const float4*)uls;
#pragma unroll
      for (int p = 0; p < 8; ++p) {
        float4 a = Mr[p]; float4 b = uu[p];
        acc = fmaf(a.x, b.x, fmaf(a.y, b.y, fmaf(a.z, b.z, fmaf(a.w, b.w, acc))));
      }
      float cm = acc;
#pragma unroll
      for (int dlt = 16; dlt; dlt >>= 1) cm = fmaxf(cm, __shfl_xor(cm, dlt, 64));
      int ex = fexp_of(cm);
      vh = ldexpf(acc, -ex);
      vo += mm + (float)ex;
    }
    float ts = trans[STOP_TAG * NT + c] * L2E;
    float tm = ts;
#pragma unroll
    for (int dlt = 16; dlt; dlt >>= 1) tm = fmaxf(tm, __shfl_xor(tm, dlt, 64));
    float term = vh * exp2f(ts - tm);
#pragma unroll
    for (int dlt = 16; dlt; dlt >>= 1) term += __shfl_xor(term, dlt, 64);
    if (tid == 0) out[0] = (vo + tm + log2f(term)) * LN2;
  }
}

extern "C" void kernel_launch(void* const* d_in, const int* in_sizes, int n_in,
                              void* d_out, int out_size, void* d_ws, size_t ws_size,
                              hipStream_t stream) {
  const float* feat = (const float*)d_in[0];
  const float* trans = (const float*)d_in[1];
  float* out = (float*)d_out;

  const int T = in_sizes[0] / NT;  // 65536

  int C = 2048;
  while (C > 512) {
    size_t fl = (size_t)C * 1056 + (size_t)(C / 16) * 1056;
    if (fl * 4 <= ws_size && (T % C) == 0 && ((T / C) % 4) == 0) break;
    C >>= 1;
  }
  const int lch = T / C;     // 32 / 64 / 128
  const int n2 = C / 16;     // 128 / 64 / 32
  const int n3 = n2 / 16;    // 8 / 4 / 2

  float* wmat = (float*)d_ws;
  float* woff = wmat + (size_t)C * 1024;
  float* w2m = woff + (size_t)C * 32;
  float* w2o = w2m + (size_t)n2 * 1024;

  crf_k1<<<C / 2, 64, (size_t)lch * 2 * NT * 4, stream>>>(feat, trans, wmat, woff, lch);
  crf_k2<<<n2, 64, 0, stream>>>(wmat, woff, w2m, w2o, 16);
  crf_k3<<<1, n3 * 64, 0, stream>>>(w2m, w2o, trans, out, n3);
}